// Round 1
// baseline (250.336 us; speedup 1.0000x reference)
//
#include <hip/hip_runtime.h>

#define EPS 1e-8f

// ---------------------------------------------------------------------------
// Problem constants (from setup_inputs): B=16, C=256, T=512, L=4096
// ---------------------------------------------------------------------------
#define BB 16
#define CC 256
#define TT 512
#define LL 4096

// Kernel 1: per-batch inclusive cumsum of w -> center = cumsum - 0.5*w,
// and nhis = -0.5 / (sigma^2 + eps) with sigma = w * sigma_scale.
__global__ void scan_kernel(const float* __restrict__ w,
                            const float* __restrict__ sigma_scale,
                            float* __restrict__ center,
                            float* __restrict__ nhis) {
    const int b = blockIdx.x;
    const int t = threadIdx.x;  // 512 threads
    __shared__ float s[TT];
    const float wv = w[b * TT + t];
    s[t] = wv;
    __syncthreads();
    // Hillis-Steele inclusive scan
    for (int off = 1; off < TT; off <<= 1) {
        float v = (t >= off) ? s[t - off] : 0.0f;
        __syncthreads();
        s[t] += v;
        __syncthreads();
    }
    center[b * TT + t] = s[t] - 0.5f * wv;
    const float sg = wv * sigma_scale[0];
    nhis[b * TT + t] = -0.5f / (sg * sg + EPS);
}

// Kernel 2: inv_den[b,l] = 1 / (sum_t exp(mu^2 * nhis) + eps)
__global__ __launch_bounds__(256)
void denom_kernel(const float* __restrict__ center,
                  const float* __restrict__ nhis,
                  float* __restrict__ inv_den) {
    const int b = blockIdx.y;
    const int l = blockIdx.x * 256 + threadIdx.x;
    __shared__ float sc[TT];
    __shared__ float sh[TT];
    for (int i = threadIdx.x; i < TT; i += 256) {
        sc[i] = center[b * TT + i];
        sh[i] = nhis[b * TT + i];
    }
    __syncthreads();
    const float pos = (float)l;
    float sum = 0.0f;
#pragma unroll 8
    for (int t = 0; t < TT; ++t) {
        const float mu = pos - sc[t];
        sum += __expf(mu * mu * sh[t]);
    }
    inv_den[b * LL + l] = 1.0f / (sum + EPS);
}

// Kernel 3: out[b,c,l] = (sum_t x[b,c,t]*xm[b,t] * W[b,t,l]) * ym[b,l]
// 64x64 output tile per block, 256 threads, 4x4 register accumulation.
// Weight tile (64t x 64l) recomputed in LDS per k-chunk.
#define TCD 64   // c tile
#define TLD 64   // l tile
#define TKD 64   // t chunk
#define LDST 68  // padded LDS stride (17 float4s -> keeps 16B alignment)

__global__ __launch_bounds__(256)
void gemm_kernel(const float* __restrict__ x,
                 const float* __restrict__ x_mask,
                 const float* __restrict__ y_mask,
                 const float* __restrict__ center,
                 const float* __restrict__ nhis,
                 const float* __restrict__ inv_den,
                 float* __restrict__ out) {
    __shared__ float xs[TKD][LDST];  // [t][c]  (x transposed)
    __shared__ float ws[TKD][LDST];  // [t][l]

    const int b  = blockIdx.z;
    const int c0 = blockIdx.y * TCD;
    const int l0 = blockIdx.x * TLD;
    const int tid = threadIdx.x;
    const int tx = tid & 15;   // l group (4 l's)
    const int ty = tid >> 4;   // c group (4 c's)

    // weight-compute mapping: 64 l's across lanes, 4 t-groups of 16
    const int lw = tid & 63;
    const int tg = tid >> 6;
    const float pos  = (float)(l0 + lw);
    const float invd = inv_den[b * LL + l0 + lw];

    // x-load mapping: 1024 float4s per tile, 4 per thread
    // f4 index = tid + 256*i ; row c_l = idx/16 ; col4 = idx%16
    float acc[4][4];
#pragma unroll
    for (int i = 0; i < 4; ++i)
#pragma unroll
        for (int j = 0; j < 4; ++j) acc[i][j] = 0.0f;

    for (int tc = 0; tc < TT; tc += TKD) {
        // ---- load x chunk (transpose into LDS), apply x_mask ----
#pragma unroll
        for (int i = 0; i < 4; ++i) {
            const int idx  = tid + 256 * i;
            const int c_l  = idx >> 4;
            const int col4 = idx & 15;
            const float4 gx = *(const float4*)&x[((size_t)(b * CC + c0 + c_l)) * TT + tc + col4 * 4];
            const float4 xm = *(const float4*)&x_mask[b * TT + tc + col4 * 4];
            xs[col4 * 4 + 0][c_l] = gx.x * xm.x;
            xs[col4 * 4 + 1][c_l] = gx.y * xm.y;
            xs[col4 * 4 + 2][c_l] = gx.z * xm.z;
            xs[col4 * 4 + 3][c_l] = gx.w * xm.w;
        }
        // ---- compute weight chunk into LDS ----
#pragma unroll
        for (int i = 0; i < 16; ++i) {
            const int t = tg * 16 + i;
            const float ct = center[b * TT + tc + t];
            const float nh = nhis[b * TT + tc + t];
            const float mu = pos - ct;
            ws[t][lw] = __expf(mu * mu * nh) * invd;
        }
        __syncthreads();
        // ---- accumulate ----
#pragma unroll 8
        for (int kt = 0; kt < TKD; ++kt) {
            const float4 a  = *(const float4*)&xs[kt][ty * 4];
            const float4 bv = *(const float4*)&ws[kt][tx * 4];
            acc[0][0] += a.x * bv.x; acc[0][1] += a.x * bv.y;
            acc[0][2] += a.x * bv.z; acc[0][3] += a.x * bv.w;
            acc[1][0] += a.y * bv.x; acc[1][1] += a.y * bv.y;
            acc[1][2] += a.y * bv.z; acc[1][3] += a.y * bv.w;
            acc[2][0] += a.z * bv.x; acc[2][1] += a.z * bv.y;
            acc[2][2] += a.z * bv.z; acc[2][3] += a.z * bv.w;
            acc[3][0] += a.w * bv.x; acc[3][1] += a.w * bv.y;
            acc[3][2] += a.w * bv.z; acc[3][3] += a.w * bv.w;
        }
        __syncthreads();
    }

    // ---- epilogue: apply y_mask, store ----
    const float4 ym = *(const float4*)&y_mask[b * LL + l0 + tx * 4];
#pragma unroll
    for (int i = 0; i < 4; ++i) {
        const int c = c0 + ty * 4 + i;
        float4 o;
        o.x = acc[i][0] * ym.x;
        o.y = acc[i][1] * ym.y;
        o.z = acc[i][2] * ym.z;
        o.w = acc[i][3] * ym.w;
        *(float4*)&out[((size_t)(b * CC + c)) * LL + l0 + tx * 4] = o;
    }
}

extern "C" void kernel_launch(void* const* d_in, const int* in_sizes, int n_in,
                              void* d_out, int out_size, void* d_ws, size_t ws_size,
                              hipStream_t stream) {
    const float* x           = (const float*)d_in[0];
    const float* w           = (const float*)d_in[1];
    const float* x_mask      = (const float*)d_in[2];
    const float* y_mask      = (const float*)d_in[3];
    const float* sigma_scale = (const float*)d_in[4];
    float* out = (float*)d_out;

    // scratch layout: center[B*T], nhis[B*T], inv_den[B*L]  (~320 KB)
    float* center  = (float*)d_ws;
    float* nhis    = center + BB * TT;
    float* inv_den = nhis + BB * TT;

    hipLaunchKernelGGL(scan_kernel, dim3(BB), dim3(TT), 0, stream,
                       w, sigma_scale, center, nhis);
    hipLaunchKernelGGL(denom_kernel, dim3(LL / 256, BB), dim3(256), 0, stream,
                       center, nhis, inv_den);
    hipLaunchKernelGGL(gemm_kernel, dim3(LL / TLD, CC / TCD, BB), dim3(256), 0, stream,
                       x, x_mask, y_mask, center, nhis, inv_den, out);
}

// Round 2
// 66.487 us; speedup vs baseline: 3.7652x; 3.7652x over previous
//
#include <hip/hip_runtime.h>
#include <hip/hip_bf16.h>

#define EPS 1e-8f

#define BB 16
#define CC 256
#define TT 512
#define LL 4096

typedef __attribute__((ext_vector_type(8))) short short8;
typedef __attribute__((ext_vector_type(4))) float f32x4;

__device__ __forceinline__ unsigned short bfbits(float f) {
    __hip_bfloat16 h = __float2bfloat16(f);
    return *(unsigned short*)&h;
}
__device__ __forceinline__ unsigned int pack2(float lo, float hi) {
    return (unsigned int)bfbits(lo) | ((unsigned int)bfbits(hi) << 16);
}

// ---------------------------------------------------------------------------
// Kernel 1: per-batch cumsum -> center = cumsum - 0.5*w ; nhis = -0.5/(sg^2+eps)
// ---------------------------------------------------------------------------
__global__ void scan_kernel(const float* __restrict__ w,
                            const float* __restrict__ sigma_scale,
                            float* __restrict__ center,
                            float* __restrict__ nhis) {
    const int b = blockIdx.x;
    const int t = threadIdx.x;  // 512 threads
    __shared__ float s[TT];
    const float wv = w[b * TT + t];
    s[t] = wv;
    __syncthreads();
    for (int off = 1; off < TT; off <<= 1) {
        float v = (t >= off) ? s[t - off] : 0.0f;
        __syncthreads();
        s[t] += v;
        __syncthreads();
    }
    center[b * TT + t] = s[t] - 0.5f * wv;
    const float sg = wv * sigma_scale[0];
    nhis[b * TT + t] = -0.5f / (sg * sg + EPS);
}

// ---------------------------------------------------------------------------
// Kernel 2: invd[b,l] = y_mask[b,l] / (sum_t exp(mu^2*nhis) + eps)
// ---------------------------------------------------------------------------
__global__ __launch_bounds__(256)
void denom_kernel(const float* __restrict__ center,
                  const float* __restrict__ nhis,
                  const float* __restrict__ y_mask,
                  float* __restrict__ invd) {
    const int b = blockIdx.y;
    const int l = blockIdx.x * 256 + threadIdx.x;
    __shared__ float sc[TT];
    __shared__ float sh[TT];
    for (int i = threadIdx.x; i < TT; i += 256) {
        sc[i] = center[b * TT + i];
        sh[i] = nhis[b * TT + i];
    }
    __syncthreads();
    const float pos = (float)l;
    float sum = 0.0f;
#pragma unroll 8
    for (int t = 0; t < TT; ++t) {
        const float mu = pos - sc[t];
        sum += __expf(mu * mu * sh[t]);
    }
    invd[b * LL + l] = y_mask[b * LL + l] / (sum + EPS);
}

// ---------------------------------------------------------------------------
// Kernel 3: MFMA bf16 GEMM.  out[b,c,l] = (sum_t xb[c,t] * Wraw[t,l]) * invd[l]
// Tile: 128 c x 128 l, K-chunk 64 t. 256 threads = 4 waves (2x2), 64x64/wave.
// LDS: xs[c][t] bf16 (pad 72), ws[l][t] bf16 (pad 72)  -> both MFMA-frag reads
// are contiguous-8-bf16 along t (ds_read_b128, 2-way bank aliasing only).
// ---------------------------------------------------------------------------
#define KC 64
#define PAD 72

__global__ __launch_bounds__(256)
void gemm_kernel(const float* __restrict__ x,
                 const float* __restrict__ x_mask,
                 const float* __restrict__ center,
                 const float* __restrict__ nhis,
                 const float* __restrict__ invd,
                 float* __restrict__ out) {
    __shared__ unsigned short xs[128][PAD];
    __shared__ unsigned short ws[128][PAD];

    const int b  = blockIdx.z;
    const int c0 = blockIdx.y * 128;
    const int l0 = blockIdx.x * 128;
    const int tid = threadIdx.x;
    const int w    = tid >> 6;
    const int lane = tid & 63;
    const int lq   = lane & 15;  // low 4 bits
    const int lg   = lane >> 4;  // k-group / row-group
    const int wr   = w >> 1;     // wave row (c half)
    const int wc   = w & 1;      // wave col (l half)

    const int bTT = b * TT;
    const size_t xrow0 = (size_t)(b * CC + c0) * TT;

    f32x4 acc[4][4];
#pragma unroll
    for (int m = 0; m < 4; ++m)
#pragma unroll
        for (int n = 0; n < 4; ++n) acc[m][n] = (f32x4)0.0f;

    for (int tc = 0; tc < TT; tc += KC) {
        __syncthreads();  // previous chunk's MFMA reads complete

        // ---- stage x chunk: 128c x 64t fp32 -> bf16, apply x_mask ----
#pragma unroll
        for (int i = 0; i < 8; ++i) {
            const int idx4 = tid + 256 * i;
            const int c    = idx4 >> 4;
            const int t4   = idx4 & 15;
            const float4 gx = *(const float4*)&x[xrow0 + (size_t)c * TT + tc + t4 * 4];
            const float4 xm = *(const float4*)&x_mask[bTT + tc + t4 * 4];
            ushort4 v;
            v.x = bfbits(gx.x * xm.x);
            v.y = bfbits(gx.y * xm.y);
            v.z = bfbits(gx.z * xm.z);
            v.w = bfbits(gx.w * xm.w);
            *(ushort4*)&xs[c][t4 * 4] = v;
        }

        // ---- compute weight chunk: 128l x 64t raw exp, bf16 ----
#pragma unroll
        for (int i = 0; i < 4; ++i) {
            const int l_loc = w * 32 + (i & 1) * 16 + lq;
            const int t0    = (i >> 1) * 32 + lg * 8;
            const float posf = (float)(l0 + l_loc);
            const float4 c0v = *(const float4*)&center[bTT + tc + t0];
            const float4 c1v = *(const float4*)&center[bTT + tc + t0 + 4];
            const float4 n0v = *(const float4*)&nhis[bTT + tc + t0];
            const float4 n1v = *(const float4*)&nhis[bTT + tc + t0 + 4];
            float mu;
            float e[8];
            mu = posf - c0v.x; e[0] = __expf(mu * mu * n0v.x);
            mu = posf - c0v.y; e[1] = __expf(mu * mu * n0v.y);
            mu = posf - c0v.z; e[2] = __expf(mu * mu * n0v.z);
            mu = posf - c0v.w; e[3] = __expf(mu * mu * n0v.w);
            mu = posf - c1v.x; e[4] = __expf(mu * mu * n1v.x);
            mu = posf - c1v.y; e[5] = __expf(mu * mu * n1v.y);
            mu = posf - c1v.z; e[6] = __expf(mu * mu * n1v.z);
            mu = posf - c1v.w; e[7] = __expf(mu * mu * n1v.w);
            uint4 p;
            p.x = pack2(e[0], e[1]);
            p.y = pack2(e[2], e[3]);
            p.z = pack2(e[4], e[5]);
            p.w = pack2(e[6], e[7]);
            *(uint4*)&ws[l_loc][t0] = p;
        }

        __syncthreads();

        // ---- MFMA: 2 k-steps of 32, 4x4 fragments of 16x16 ----
#pragma unroll
        for (int kk = 0; kk < 2; ++kk) {
            short8 af[4], bf[4];
#pragma unroll
            for (int m = 0; m < 4; ++m)
                af[m] = *(const short8*)&xs[wr * 64 + m * 16 + lq][kk * 32 + lg * 8];
#pragma unroll
            for (int n = 0; n < 4; ++n)
                bf[n] = *(const short8*)&ws[wc * 64 + n * 16 + lq][kk * 32 + lg * 8];
#pragma unroll
            for (int m = 0; m < 4; ++m)
#pragma unroll
                for (int n = 0; n < 4; ++n)
                    acc[m][n] = __builtin_amdgcn_mfma_f32_16x16x32_bf16(
                        af[m], bf[n], acc[m][n], 0, 0, 0);
        }
    }

    // ---- epilogue: scale by invd (= y_mask/denom), store fp32 ----
    const int bLL = b * LL;
    float scale[4];
#pragma unroll
    for (int n = 0; n < 4; ++n)
        scale[n] = invd[bLL + l0 + wc * 64 + n * 16 + lq];

    const size_t obase = (size_t)(b * CC) * LL;
#pragma unroll
    for (int m = 0; m < 4; ++m) {
#pragma unroll
        for (int r = 0; r < 4; ++r) {
            const int c = c0 + wr * 64 + m * 16 + lg * 4 + r;
            const size_t rowb = obase + (size_t)c * LL + l0 + wc * 64;
#pragma unroll
            for (int n = 0; n < 4; ++n)
                out[rowb + n * 16 + lq] = acc[m][n][r] * scale[n];
        }
    }
}

extern "C" void kernel_launch(void* const* d_in, const int* in_sizes, int n_in,
                              void* d_out, int out_size, void* d_ws, size_t ws_size,
                              hipStream_t stream) {
    const float* x           = (const float*)d_in[0];
    const float* w           = (const float*)d_in[1];
    const float* x_mask      = (const float*)d_in[2];
    const float* y_mask      = (const float*)d_in[3];
    const float* sigma_scale = (const float*)d_in[4];
    float* out = (float*)d_out;

    float* center = (float*)d_ws;
    float* nhis   = center + BB * TT;
    float* invd   = nhis + BB * TT;

    hipLaunchKernelGGL(scan_kernel, dim3(BB), dim3(TT), 0, stream,
                       w, sigma_scale, center, nhis);
    hipLaunchKernelGGL(denom_kernel, dim3(LL / 256, BB), dim3(256), 0, stream,
                       center, nhis, y_mask, invd);
    hipLaunchKernelGGL(gemm_kernel, dim3(LL / 128, CC / 128, BB), dim3(256), 0, stream,
                       x, x_mask, center, nhis, invd, out);
}

// Round 3
// 48.309 us; speedup vs baseline: 5.1820x; 1.3763x over previous
//
#include <hip/hip_runtime.h>
#include <hip/hip_bf16.h>

#define EPS 1e-8f

#define BB 16
#define CC 256
#define TT 512
#define LL 4096
#define TLB 64   // l-tile
#define KC  64   // t-chunk
#define PADS 72  // LDS stride in bf16 elems

typedef __attribute__((ext_vector_type(8))) short short8;
typedef __attribute__((ext_vector_type(4))) float f32x4;

__device__ __forceinline__ unsigned short bfbits(float f) {
    __hip_bfloat16 h = __float2bfloat16(f);
    return *(unsigned short*)&h;
}
__device__ __forceinline__ unsigned int pack2(float lo, float hi) {
    return (unsigned int)bfbits(lo) | ((unsigned int)bfbits(hi) << 16);
}

// ---------------------------------------------------------------------------
// Kernel 1: per-batch cumsum -> center, nhis = -0.5/(sg^2+eps), band delta
// ---------------------------------------------------------------------------
__global__ __launch_bounds__(512)
void scan_kernel(const float* __restrict__ w,
                 const float* __restrict__ sigma_scale,
                 float* __restrict__ center,
                 float* __restrict__ nhis,
                 float* __restrict__ delta) {
    const int b = blockIdx.x;
    const int t = threadIdx.x;  // 512
    __shared__ float s[TT];
    __shared__ float wmaxs[8];
    const float wv = w[b * TT + t];
    s[t] = wv;
    __syncthreads();
    for (int off = 1; off < TT; off <<= 1) {
        float v = (t >= off) ? s[t - off] : 0.0f;
        __syncthreads();
        s[t] += v;
        __syncthreads();
    }
    const float ss = sigma_scale[0];
    center[b * TT + t] = s[t] - 0.5f * wv;
    const float sg = wv * ss;
    nhis[b * TT + t] = -0.5f / (sg * sg + EPS);
    // block max of w -> band half-width
    float m = wv;
#pragma unroll
    for (int o = 1; o < 64; o <<= 1) m = fmaxf(m, __shfl_xor(m, o));
    if ((t & 63) == 0) wmaxs[t >> 6] = m;
    __syncthreads();
    if (t == 0) {
        float mm = wmaxs[0];
#pragma unroll
        for (int i = 1; i < 8; ++i) mm = fmaxf(mm, wmaxs[i]);
        // cutoff |mu| > 8*sigma_eff  ->  excluded exp <= e^-32 ~ 1.3e-14
        delta[b] = 8.0f * (mm * ss + 1e-4f) + 1.0f;
    }
}

// ---------------------------------------------------------------------------
// Kernel 2: fused banded MFMA GEMM + denominator.
// Block: 256c x 64l, K-band over t in chunks of 64.
// 256 threads = 4 waves; wave wv owns c-range [wv*64, wv*64+64).
// ---------------------------------------------------------------------------
__global__ __launch_bounds__(256, 3)
void fused_kernel(const float* __restrict__ x,
                  const float* __restrict__ x_mask,
                  const float* __restrict__ y_mask,
                  const float* __restrict__ center,
                  const float* __restrict__ nhis,
                  const float* __restrict__ delta,
                  float* __restrict__ out) {
    __shared__ unsigned short xs[CC][PADS];   // 36 KB  [c][t]
    __shared__ unsigned short ws[TLB][PADS];  //  9 KB  [l][t]
    __shared__ float cen_s[TT];               //  2 KB
    __shared__ float nh_s[TT];                //  2 KB
    __shared__ float dsum[TLB];
    __shared__ float sscale[TLB];
    __shared__ int tmin_s, tmax_s;

    const int b   = blockIdx.y;
    const int l0  = blockIdx.x * TLB;
    const int tid = threadIdx.x;
    const int lane = tid & 63;
    const int wv   = tid >> 6;
    const int lq   = lane & 15;
    const int lg   = lane >> 4;
    const int bTT  = b * TT;

    if (tid == 0) { tmin_s = TT; tmax_s = -1; }
    for (int i = tid; i < TT; i += 256) {
        cen_s[i] = center[bTT + i];
        nh_s[i]  = nhis[bTT + i];
    }
    __syncthreads();

    const float D  = delta[b];
    const float lo = (float)l0 - D;
    const float hi = (float)(l0 + TLB - 1) + D;
    for (int i = tid; i < TT; i += 256) {
        const float c = cen_s[i];
        if (c >= lo && c <= hi) {
            atomicMin(&tmin_s, i);
            atomicMax(&tmax_s, i);
        }
    }
    __syncthreads();
    const int tlo = tmin_s & ~(KC - 1);
    const int thi = (tmax_s >= 0) ? ((tmax_s & ~(KC - 1)) + KC) : 0;  // exclusive

    f32x4 acc[4][4];
#pragma unroll
    for (int m = 0; m < 4; ++m)
#pragma unroll
        for (int n = 0; n < 4; ++n) acc[m][n] = (f32x4)0.0f;
    float p0 = 0.0f, p1 = 0.0f;

    const size_t xbase = (size_t)b * CC * TT;

    for (int tc = tlo; tc < thi; tc += KC) {
        __syncthreads();  // previous chunk's LDS reads done

        // ---- stage x chunk: 256c x 64t fp32 -> bf16, apply x_mask ----
#pragma unroll
        for (int i = 0; i < 16; ++i) {
            const int idx4 = tid + 256 * i;
            const int c    = idx4 >> 4;
            const int t4   = idx4 & 15;
            const float4 gx = *(const float4*)&x[xbase + (size_t)c * TT + tc + t4 * 4];
            const float4 xm = *(const float4*)&x_mask[bTT + tc + t4 * 4];
            ushort4 v;
            v.x = bfbits(gx.x * xm.x);
            v.y = bfbits(gx.y * xm.y);
            v.z = bfbits(gx.z * xm.z);
            v.w = bfbits(gx.w * xm.w);
            *(ushort4*)&xs[c][t4 * 4] = v;
        }

        // ---- weights: 64l x 64t raw exp -> bf16 LDS; accumulate denom ----
#pragma unroll
        for (int i = 0; i < 2; ++i) {
            const int slot  = tid + 256 * i;
            const int tg    = slot & 7;
            const int l_loc = slot >> 3;
            const int t0    = tc + tg * 8;
            const float posf = (float)(l0 + l_loc);
            const float4 c0v = *(const float4*)&cen_s[t0];
            const float4 c1v = *(const float4*)&cen_s[t0 + 4];
            const float4 n0v = *(const float4*)&nh_s[t0];
            const float4 n1v = *(const float4*)&nh_s[t0 + 4];
            float mu, e0, e1, e2, e3, e4, e5, e6, e7;
            mu = posf - c0v.x; e0 = __expf(mu * mu * n0v.x);
            mu = posf - c0v.y; e1 = __expf(mu * mu * n0v.y);
            mu = posf - c0v.z; e2 = __expf(mu * mu * n0v.z);
            mu = posf - c0v.w; e3 = __expf(mu * mu * n0v.w);
            mu = posf - c1v.x; e4 = __expf(mu * mu * n1v.x);
            mu = posf - c1v.y; e5 = __expf(mu * mu * n1v.y);
            mu = posf - c1v.z; e6 = __expf(mu * mu * n1v.z);
            mu = posf - c1v.w; e7 = __expf(mu * mu * n1v.w);
            const float psum = ((e0 + e1) + (e2 + e3)) + ((e4 + e5) + (e6 + e7));
            if (i == 0) p0 += psum; else p1 += psum;
            uint4 pk;
            pk.x = pack2(e0, e1);
            pk.y = pack2(e2, e3);
            pk.z = pack2(e4, e5);
            pk.w = pack2(e6, e7);
            *(uint4*)&ws[l_loc][tg * 8] = pk;
        }

        __syncthreads();

        // ---- MFMA ----
#pragma unroll
        for (int kk = 0; kk < 2; ++kk) {
            short8 af[4], bfr[4];
#pragma unroll
            for (int m = 0; m < 4; ++m)
                af[m] = *(const short8*)&xs[wv * 64 + m * 16 + lq][kk * 32 + lg * 8];
#pragma unroll
            for (int n = 0; n < 4; ++n)
                bfr[n] = *(const short8*)&ws[n * 16 + lq][kk * 32 + lg * 8];
#pragma unroll
            for (int m = 0; m < 4; ++m)
#pragma unroll
                for (int n = 0; n < 4; ++n)
                    acc[m][n] = __builtin_amdgcn_mfma_f32_16x16x32_bf16(
                        af[m], bfr[n], acc[m][n], 0, 0, 0);
        }
    }

    // ---- denominator: 8-lane groups share one l; reduce and publish ----
    float s0 = p0, s1 = p1;
#pragma unroll
    for (int o = 1; o < 8; o <<= 1) {
        s0 += __shfl_xor(s0, o);
        s1 += __shfl_xor(s1, o);
    }
    if ((tid & 7) == 0) {
        dsum[tid >> 3]        = s0;
        dsum[(tid >> 3) + 32] = s1;
    }
    __syncthreads();
    if (tid < TLB)
        sscale[tid] = y_mask[b * LL + l0 + tid] / (dsum[tid] + EPS);
    __syncthreads();

    // ---- epilogue ----
    float sc[4];
#pragma unroll
    for (int n = 0; n < 4; ++n) sc[n] = sscale[n * 16 + lq];

    const size_t obase = (size_t)b * CC * LL + l0;
#pragma unroll
    for (int m = 0; m < 4; ++m) {
#pragma unroll
        for (int r = 0; r < 4; ++r) {
            const int c = wv * 64 + m * 16 + lg * 4 + r;
            float* op = &out[obase + (size_t)c * LL];
#pragma unroll
            for (int n = 0; n < 4; ++n)
                op[n * 16 + lq] = acc[m][n][r] * sc[n];
        }
    }
}

extern "C" void kernel_launch(void* const* d_in, const int* in_sizes, int n_in,
                              void* d_out, int out_size, void* d_ws, size_t ws_size,
                              hipStream_t stream) {
    const float* x           = (const float*)d_in[0];
    const float* w           = (const float*)d_in[1];
    const float* x_mask      = (const float*)d_in[2];
    const float* y_mask      = (const float*)d_in[3];
    const float* sigma_scale = (const float*)d_in[4];
    float* out = (float*)d_out;

    float* center = (float*)d_ws;
    float* nhis   = center + BB * TT;
    float* delta  = nhis + BB * TT;

    hipLaunchKernelGGL(scan_kernel, dim3(BB), dim3(TT), 0, stream,
                       w, sigma_scale, center, nhis, delta);
    hipLaunchKernelGGL(fused_kernel, dim3(LL / TLB, BB), dim3(256), 0, stream,
                       x, x_mask, y_mask, center, nhis, delta, out);
}

// Round 4
// 28.252 us; speedup vs baseline: 8.8609x; 1.7099x over previous
//
#include <hip/hip_runtime.h>
#include <hip/hip_bf16.h>

#define EPS 1e-8f

#define BB 16
#define CC 256
#define TT 512
#define LL 4096
#define KC  32    // t-chunk
#define TCB 128   // c-tile
#define TLB 64    // l-tile
#define XR  40    // LDS row stride in ushorts (80B = 5*16B: odd -> conflict-free-ish)

typedef __attribute__((ext_vector_type(8))) short short8;
typedef __attribute__((ext_vector_type(4))) float f32x4;

__device__ __forceinline__ unsigned short bfbits(float f) {
    __hip_bfloat16 h = __float2bfloat16(f);
    return *(unsigned short*)&h;
}
__device__ __forceinline__ unsigned int pack2(float lo, float hi) {
    return (unsigned int)bfbits(lo) | ((unsigned int)bfbits(hi) << 16);
}

// ---------------------------------------------------------------------------
// Kernel 1: per-batch cumsum via wave shuffle scan (no LDS ping-pong).
// center = cumsum - 0.5*w ; nhis = -0.5/(sg^2+eps) ; delta = band half-width
// ---------------------------------------------------------------------------
__global__ __launch_bounds__(512)
void scan_kernel(const float* __restrict__ w,
                 const float* __restrict__ sigma_scale,
                 float* __restrict__ center,
                 float* __restrict__ nhis,
                 float* __restrict__ delta) {
    const int b = blockIdx.x;
    const int t = threadIdx.x;       // 512
    const int lane = t & 63;
    const int wid  = t >> 6;
    __shared__ float part[8], offs[8], wmx[8];

    const float wv = w[b * TT + t];
    float v = wv;
#pragma unroll
    for (int o = 1; o < 64; o <<= 1) {
        float u = __shfl_up(v, o);
        if (lane >= o) v += u;
    }
    float m = wv;
#pragma unroll
    for (int o = 1; o < 64; o <<= 1) m = fmaxf(m, __shfl_xor(m, o));
    if (lane == 63) part[wid] = v;
    if (lane == 0)  wmx[wid] = m;
    __syncthreads();
    const float ss = sigma_scale[0];
    if (t == 0) {
        float run = 0.0f, mm = 0.0f;
#pragma unroll
        for (int i = 0; i < 8; ++i) {
            offs[i] = run;
            run += part[i];
            mm = fmaxf(mm, wmx[i]);
        }
        delta[b] = 8.0f * (mm * ss + 1e-4f) + 1.0f;
    }
    __syncthreads();
    v += offs[wid];
    center[b * TT + t] = v - 0.5f * wv;
    const float sg = wv * ss;
    nhis[b * TT + t] = -0.5f / (sg * sg + EPS);
}

// ---------------------------------------------------------------------------
// Kernel 2: banded fused GEMM, software-pipelined (T14 async-stage).
// Block: 128c x 64l, K-band in chunks of 32 t. 256 thr = 4 waves, 32c/wave.
// Double-buffered xs/ws; one barrier per chunk; loads issued a chunk ahead.
// ---------------------------------------------------------------------------

#define ISSUE(tc_)                                                              \
    {                                                                           \
        _Pragma("unroll")                                                       \
        for (int i = 0; i < 4; ++i) {                                           \
            const int idx4 = tid + 256 * i;                                     \
            const int c    = idx4 >> 3;                                         \
            const int t4   = idx4 & 7;                                          \
            gx[i] = *(const float4*)&x[xbase + (size_t)c * TT + (tc_) + t4 * 4];\
            gm[i] = *(const float4*)&x_mask[bTT + (tc_) + t4 * 4];              \
        }                                                                       \
    }

#define WRITEX(buf_)                                                            \
    {                                                                           \
        _Pragma("unroll")                                                       \
        for (int i = 0; i < 4; ++i) {                                           \
            const int idx4 = tid + 256 * i;                                     \
            const int c    = idx4 >> 3;                                         \
            const int t4   = idx4 & 7;                                          \
            ushort4 v4;                                                         \
            v4.x = bfbits(gx[i].x * gm[i].x);                                   \
            v4.y = bfbits(gx[i].y * gm[i].y);                                   \
            v4.z = bfbits(gx[i].z * gm[i].z);                                   \
            v4.w = bfbits(gx[i].w * gm[i].w);                                   \
            *(ushort4*)&xs[buf_][c][t4 * 4] = v4;                               \
        }                                                                       \
    }

#define EXPW(tc_, buf_)                                                         \
    {                                                                           \
        _Pragma("unroll")                                                       \
        for (int i = 0; i < 2; ++i) {                                           \
            const int slot  = tid + 256 * i;                                    \
            const int l_loc = slot >> 3;                                        \
            const int t4    = slot & 7;                                         \
            const int t0    = (tc_) + t4 * 4;                                   \
            const float4 cv = *(const float4*)&center[bTT + t0];                \
            const float4 nv = *(const float4*)&nhis[bTT + t0];                  \
            const float posf = (float)(l0 + l_loc);                             \
            float mu, e0, e1, e2, e3;                                           \
            mu = posf - cv.x; e0 = __expf(mu * mu * nv.x);                      \
            mu = posf - cv.y; e1 = __expf(mu * mu * nv.y);                      \
            mu = posf - cv.z; e2 = __expf(mu * mu * nv.z);                      \
            mu = posf - cv.w; e3 = __expf(mu * mu * nv.w);                      \
            const float ps = (e0 + e1) + (e2 + e3);                             \
            if (i == 0) p0 += ps; else p1 += ps;                                \
            uint2 pk;                                                           \
            pk.x = pack2(e0, e1);                                               \
            pk.y = pack2(e2, e3);                                               \
            *(uint2*)&ws[buf_][l_loc][t4 * 4] = pk;                             \
        }                                                                       \
    }

#define MFMA_STEP(buf_)                                                         \
    {                                                                           \
        short8 af[2], bfr[4];                                                   \
        _Pragma("unroll")                                                       \
        for (int m = 0; m < 2; ++m)                                             \
            af[m] = *(const short8*)&xs[buf_][wv * 32 + m * 16 + lq][lg * 8];   \
        _Pragma("unroll")                                                       \
        for (int n = 0; n < 4; ++n)                                             \
            bfr[n] = *(const short8*)&ws[buf_][n * 16 + lq][lg * 8];            \
        _Pragma("unroll")                                                       \
        for (int m = 0; m < 2; ++m)                                             \
            _Pragma("unroll")                                                   \
            for (int n = 0; n < 4; ++n)                                         \
                acc[m][n] = __builtin_amdgcn_mfma_f32_16x16x32_bf16(            \
                    af[m], bfr[n], acc[m][n], 0, 0, 0);                         \
    }

__global__ __launch_bounds__(256, 4)
void fused_kernel(const float* __restrict__ x,
                  const float* __restrict__ x_mask,
                  const float* __restrict__ y_mask,
                  const float* __restrict__ center,
                  const float* __restrict__ nhis,
                  const float* __restrict__ delta,
                  float* __restrict__ out) {
    __shared__ unsigned short xs[2][TCB][XR];  // 20.0 KB
    __shared__ unsigned short ws[2][TLB][XR];  // 10.0 KB
    __shared__ float dsum[TLB];
    __shared__ float sscale[TLB];
    __shared__ int tmin_s, tmax_s;

    // XCD-chunked swizzle: 2048 blocks, 8 XCDs -> XCD k owns batches 2k,2k+1.
    const int gid = blockIdx.x;
    const int lid = (gid & 7) * 256 + (gid >> 3);
    const int b   = lid >> 7;
    const int rr_ = lid & 127;
    const int l0  = (rr_ >> 1) * TLB;
    const int c0  = (rr_ & 1) * TCB;

    const int tid  = threadIdx.x;
    const int lane = tid & 63;
    const int wv   = tid >> 6;
    const int lq   = lane & 15;
    const int lg   = lane >> 4;
    const int bTT  = b * TT;
    const size_t xbase = (size_t)(b * CC + c0) * TT;

    if (tid == 0) { tmin_s = TT; tmax_s = -1; }
    __syncthreads();
    const float D  = delta[b];
    const float lo = (float)l0 - D;
    const float hi = (float)(l0 + TLB - 1) + D;
#pragma unroll
    for (int i = 0; i < 2; ++i) {
        const int tt = tid + 256 * i;
        const float c = center[bTT + tt];
        if (c >= lo && c <= hi) {
            atomicMin(&tmin_s, tt);
            atomicMax(&tmax_s, tt);
        }
    }
    __syncthreads();
    const int tlo = tmin_s & ~(KC - 1);
    const int nch = (tmax_s >= 0) ? ((((tmax_s & ~(KC - 1)) + KC) - tlo) / KC) : 0;

    f32x4 acc[2][4];
#pragma unroll
    for (int m = 0; m < 2; ++m)
#pragma unroll
        for (int n = 0; n < 4; ++n) acc[m][n] = (f32x4)0.0f;
    float p0 = 0.0f, p1 = 0.0f;

    float4 gx[4], gm[4];

    if (nch > 0) {
        ISSUE(tlo);
        EXPW(tlo, 0);
        WRITEX(0);
        __syncthreads();
        for (int i = 0; i < nch; ++i) {
            const int cur = i & 1;
            const int tc1 = tlo + (i + 1) * KC;
            if (i + 1 < nch) {
                ISSUE(tc1);
                EXPW(tc1, cur ^ 1);
            }
            MFMA_STEP(cur);
            if (i + 1 < nch) WRITEX(cur ^ 1);
            __syncthreads();
        }
    }

    // ---- denominator: 8 lanes (t-groups) per l; reduce, publish ----
#pragma unroll
    for (int o = 1; o < 8; o <<= 1) {
        p0 += __shfl_xor(p0, o);
        p1 += __shfl_xor(p1, o);
    }
    if ((tid & 7) == 0) {
        dsum[tid >> 3]        = p0;
        dsum[(tid >> 3) + 32] = p1;
    }
    __syncthreads();
    if (tid < TLB)
        sscale[tid] = y_mask[b * LL + l0 + tid] / (dsum[tid] + EPS);
    __syncthreads();

    // ---- epilogue ----
    float sc[4];
#pragma unroll
    for (int n = 0; n < 4; ++n) sc[n] = sscale[n * 16 + lq];

    const size_t obase = (size_t)(b * CC + c0) * LL + l0;
#pragma unroll
    for (int m = 0; m < 2; ++m) {
#pragma unroll
        for (int r = 0; r < 4; ++r) {
            const int c = wv * 32 + m * 16 + lg * 4 + r;
            float* op = &out[obase + (size_t)c * LL];
#pragma unroll
            for (int n = 0; n < 4; ++n)
                op[n * 16 + lq] = acc[m][n][r] * sc[n];
        }
    }
}

extern "C" void kernel_launch(void* const* d_in, const int* in_sizes, int n_in,
                              void* d_out, int out_size, void* d_ws, size_t ws_size,
                              hipStream_t stream) {
    const float* x           = (const float*)d_in[0];
    const float* w           = (const float*)d_in[1];
    const float* x_mask      = (const float*)d_in[2];
    const float* y_mask      = (const float*)d_in[3];
    const float* sigma_scale = (const float*)d_in[4];
    float* out = (float*)d_out;

    float* center = (float*)d_ws;
    float* nhis   = center + BB * TT;
    float* delta  = nhis + BB * TT;

    hipLaunchKernelGGL(scan_kernel, dim3(BB), dim3(512), 0, stream,
                       w, sigma_scale, center, nhis, delta);
    hipLaunchKernelGGL(fused_kernel, dim3((LL / TLB) * (CC / TCB) * BB), dim3(256), 0, stream,
                       x, x_mask, y_mask, center, nhis, delta, out);
}